// Round 16
// baseline (616.038 us; speedup 1.0000x reference)
//
#include <hip/hip_runtime.h>
#include <stdint.h>

#define N_TOK 4096
#define CDIM  2048
#define NEXP  8
#define IDIM  1408
#define ISDIM 2816
#define CAP   2048
#define ICAT  2816   // interleaved [w1;w2] rows per expert (128-row groups)
#define SCAT  5632   // interleaved [sw1;sw2] rows (2 col-half sections)

typedef __attribute__((ext_vector_type(8))) short bf16x8;
typedef __attribute__((ext_vector_type(4))) float f32x4;

#define GLOAD16(gp, lp) __builtin_amdgcn_global_load_lds( \
    (const __attribute__((address_space(1))) void*)(gp),  \
    (__attribute__((address_space(3))) void*)(lp), 16, 0, 0)

__device__ __forceinline__ unsigned short f2bf(float f) {
  union { float f; unsigned u; } c; c.f = f;
  return (unsigned short)((c.u + 0x7FFFu + ((c.u >> 16) & 1u)) >> 16);
}
__device__ __forceinline__ float bf2f(unsigned short h) {
  union { unsigned u; float f; } c; c.u = (unsigned)h << 16;
  return c.f;
}

__device__ __forceinline__ int xcd_swizzle(int orig, int nwg) {
  int q = nwg >> 3, r = nwg & 7;
  int xcd = orig & 7, idx = orig >> 3;
  return (xcd < r ? xcd * (q + 1) : r * (q + 1) + (xcd - r) * q) + idx;
}

// ---------------- single fused fp32 -> bf16 convert, all tensors ----------------
__global__ __launch_bounds__(256) void cvt_all(
    const float* __restrict__ x, const float* __restrict__ w1,
    const float* __restrict__ w2, const float* __restrict__ w3,
    const float* __restrict__ sw1, const float* __restrict__ sw2,
    const float* __restrict__ sw3,
    unsigned short* __restrict__ xb, unsigned short* __restrict__ wcat,
    unsigned short* __restrict__ w3b, unsigned short* __restrict__ swcat,
    unsigned short* __restrict__ sw3b) {
  const int b = blockIdx.x;
  const int t = threadIdx.x;
  const float* src;
  unsigned short* dst;
  if (b < 4096) {
    src = x + (size_t)b * 2048;  dst = xb + (size_t)b * 2048;
  } else if (b < 15360) {
    size_t o = (size_t)(b - 4096) * 2048;  src = w3 + o;  dst = w3b + o;
  } else if (b < 18176) {
    size_t o = (size_t)(b - 15360) * 2048; src = sw3 + o; dst = sw3b + o;
  } else if (b < 40704) {
    int g = b - 18176;
    int e = g / 2816, r = g - e * 2816;
    int dr;
    if (r < 1408) { src = w1 + ((size_t)e * 1408 + r) * 2048; dr = (r >> 7) * 256 + (r & 127); }
    else { int r2 = r - 1408; src = w2 + ((size_t)e * 1408 + r2) * 2048; dr = (r2 >> 7) * 256 + 128 + (r2 & 127); }
    dst = wcat + ((size_t)e * ICAT + dr) * 2048;
  } else {
    int g = b - 40704;
    int dr;
    if (g < 2816) {
      int zn = g >= 1408, rr = g - zn * 1408;
      src = sw1 + (size_t)g * 2048;
      dr = zn * 2816 + (rr >> 7) * 256 + (rr & 127);
    } else {
      int r = g - 2816;
      int zn = r >= 1408, rr = r - zn * 1408;
      src = sw2 + (size_t)r * 2048;
      dr = zn * 2816 + (rr >> 7) * 256 + 128 + (rr & 127);
    }
    dst = swcat + (size_t)dr * 2048;
  }
  size_t i = (size_t)t * 8;
  float4 v0 = *(const float4*)(src + i);
  float4 v1 = *(const float4*)(src + i + 4);
  bf16x8 o;
  o[0] = (short)f2bf(v0.x); o[1] = (short)f2bf(v0.y);
  o[2] = (short)f2bf(v0.z); o[3] = (short)f2bf(v0.w);
  o[4] = (short)f2bf(v1.x); o[5] = (short)f2bf(v1.y);
  o[6] = (short)f2bf(v1.z); o[7] = (short)f2bf(v1.w);
  *(bf16x8*)(dst + i) = o;
}

// ---------------- routing (also fills per-slot weights) ----------------
__global__ __launch_bounds__(64) void routing_kernel(
    const float* __restrict__ x, const float* __restrict__ gw,
    int* __restrict__ counts, int* __restrict__ list,
    float* __restrict__ wslot) {
  const int n = blockIdx.x;
  const int lane = threadIdx.x;
  const float* xr = x + (size_t)n * CDIM;
  float s[NEXP];
#pragma unroll
  for (int e = 0; e < NEXP; e++) s[e] = 0.f;
  for (int c = lane; c < CDIM; c += 64) {
    float xv = xr[c];
#pragma unroll
    for (int e = 0; e < NEXP; e++) s[e] += xv * gw[e * CDIM + c];
  }
#pragma unroll
  for (int e = 0; e < NEXP; e++) {
    float v = s[e];
    for (int o = 32; o > 0; o >>= 1) v += __shfl_down(v, o);
    s[e] = v;
  }
  if (lane == 0) {
    float mx = s[0];
#pragma unroll
    for (int e = 1; e < NEXP; e++) mx = fmaxf(mx, s[e]);
    float p[NEXP], sum = 0.f;
#pragma unroll
    for (int e = 0; e < NEXP; e++) { p[e] = __expf(s[e] - mx); sum += p[e]; }
    int i0 = 0;
#pragma unroll
    for (int e = 1; e < NEXP; e++) if (p[e] > p[i0]) i0 = e;
    int i1 = (i0 == 0) ? 1 : 0;
#pragma unroll
    for (int e = 0; e < NEXP; e++) if (e != i0 && p[e] > p[i1]) i1 = e;
    float inv = 1.f / sum;
    int s0 = atomicAdd(&counts[i0], 1);
    int s1 = atomicAdd(&counts[i1], 1);
    if (s0 < CAP) { list[i0 * CAP + s0] = n; wslot[i0 * CAP + s0] = p[i0] * inv; }
    if (s1 < CAP) { list[i1 * CAP + s1] = n; wslot[i1 * CAP + s1] = p[i1] * inv; }
  }
}

// ---------------- unified 8-phase deep-pipelined GEMM: Out = A @ B^T ----------------
// 256x256 tile, BK=64 (2 K-halves of 64B/row), 512 threads (8 waves, 2M x 4N).
// Best-measured core (R8/R15, 591us): 2 gloads per phase (stageA/stageB split),
// ledger-exact vmcnt(8)/(4)/(0); T2 both-sides swizzle; setprio around MFMA;
// m225 accumulator recipe; fc epilogue h2-exchange XOR-swizzled (conflict-free).
// R16: proj epilogue accumulates DIRECTLY into y via f32 atomicAdd
// (eo/ysf buffers + combine kernel deleted; y pre-zeroed by memsetAsync).
template <int PHASE>
__global__ __launch_bounds__(512) void moe_gemm(
    const unsigned short* __restrict__ xb,
    const unsigned short* __restrict__ swcat,
    const unsigned short* __restrict__ wcat,
    unsigned short* __restrict__ hs_out,
    unsigned short* __restrict__ he_out,
    const unsigned short* __restrict__ hs,
    const unsigned short* __restrict__ sw3b,
    const unsigned short* __restrict__ he,
    const unsigned short* __restrict__ w3b,
    float* __restrict__ yout,
    const float* __restrict__ wslot,
    const int* __restrict__ list,
    const int* __restrict__ counts) {
  const int z = blockIdx.z;
  const unsigned short *A, *B;
  unsigned short* O = nullptr;
  float* Of = nullptr;
  int Ka, ldo = CDIM;
  int cnt = 1 << 30;
  const int* lst = nullptr;
  const float* wsl = nullptr;
  int Mt, Nt;
  bool gath = false;
  if (PHASE == 1) {
    Mt = 8; Nt = 11; Ka = CDIM;
    if (z < 4) {
      int zm = z >> 1, zn = z & 1;
      A = xb + (size_t)zm * 2048 * CDIM;
      B = swcat + (size_t)zn * 2816 * CDIM;
      O = hs_out + (size_t)zm * 2048 * ISDIM + (size_t)zn * 1408;
      ldo = ISDIM;
    } else {
      int e = z - 4;
      cnt = counts[e]; if (cnt > CAP) cnt = CAP;
      lst = list + e * CAP;
      gath = true;
      A = xb;
      B = wcat + (size_t)e * ICAT * CDIM;
      O = he_out + (size_t)e * CAP * IDIM;
      ldo = IDIM;
    }
  } else {
    Mt = 8; Nt = 8;
    if (z < 2) {
      Ka = ISDIM;
      A = hs + (size_t)z * 2048 * ISDIM;
      B = sw3b;
      Of = yout + (size_t)z * 2048 * CDIM;   // direct atomic accumulation
    } else {
      int e = z - 2;
      cnt = counts[e]; if (cnt > CAP) cnt = CAP;
      Ka = IDIM;
      A = he + (size_t)e * CAP * IDIM;
      B = w3b + (size_t)e * CDIM * IDIM;
      lst = list + e * CAP;
      wsl = wslot + e * CAP;
    }
  }
  const int wg = xcd_swizzle(blockIdx.x, Mt * Nt);
  const int mt = wg % Mt, nt = wg / Mt;
  if (mt * 256 >= cnt) return;

  __shared__ __align__(16) char lds[2][2][2][16384]; // [buf][A|B][kk][256x64B]

  const int tid = threadIdx.x;
  const int srow = tid >> 2;
  const int c16  = (tid & 3) << 4;
  const int scol = c16 ^ (((srow >> 1) & 3) << 4);
  const char* aS[2];
  const char* bS[2];
#pragma unroll
  for (int j = 0; j < 2; j++) {
    int ar = mt * 256 + j * 128 + srow;
    if (PHASE == 1 && gath) ar = (ar < cnt) ? lst[ar] : lst[0];
    aS[j] = (const char*)A + (size_t)ar * Ka * 2 + scol;
    int br = nt * 256 + j * 128 + srow;
    bS[j] = (const char*)B + (size_t)br * Ka * 2 + scol;
  }
  auto stageA = [&](int buf, int kt, int h) {
    size_t kb = (size_t)kt * 128 + (size_t)(h << 6);
    char* aD = &lds[buf][0][h][0] + tid * 16;
    GLOAD16(aS[0] + kb, aD);
    GLOAD16(aS[1] + kb, aD + 8192);
  };
  auto stageB = [&](int buf, int kt, int h) {
    size_t kb = (size_t)kt * 128 + (size_t)(h << 6);
    char* bD = &lds[buf][1][h][0] + tid * 16;
    GLOAD16(bS[0] + kb, bD);
    GLOAD16(bS[1] + kb, bD + 8192);
  };

  const int lane = tid & 63, wid = tid >> 6;
  const int wr = wid >> 2, wc = wid & 3;   // 2 x 4 wave grid, per-wave 128x64
  const int lrow = lane & 15;
  const int klane = (lane >> 4) << 4;
  const int rsw = ((lrow >> 1) & 3) << 4;
  const int aOff = (wr * 128 + lrow) * 64 + (klane ^ rsw);
  const int bOff = (wc * 64 + lrow) * 64 + (klane ^ rsw);

  f32x4 acc[8][4];
#pragma unroll
  for (int mf = 0; mf < 8; mf++)
#pragma unroll
    for (int nf = 0; nf < 4; nf++) acc[mf][nf] = (f32x4){0.f, 0.f, 0.f, 0.f};

  // prologue: (0,kk0),(0,kk1),(1,kk0) staged; drain (0,kk0) [8 newer]
  stageA(0, 0, 0); stageB(0, 0, 0);
  stageA(0, 0, 1); stageB(0, 0, 1);
  stageA(1, 1, 0); stageB(1, 1, 0);
  asm volatile("s_waitcnt vmcnt(8)" ::: "memory");
  __builtin_amdgcn_s_barrier();

#define MFMA_Q(MB)                                                             \
  _Pragma("unroll")                                                            \
  for (int nf = 0; nf < 4; nf++)                                               \
    _Pragma("unroll")                                                          \
    for (int m = 0; m < 4; m++)                                                \
      acc[(MB) * 4 + m][nf] = __builtin_amdgcn_mfma_f32_16x16x32_bf16(         \
          aR[m], bR[nf], acc[(MB) * 4 + m][nf], 0, 0, 0);

  const int ntk = Ka >> 6;
  for (int t = 0; t < ntk; t++) {
    const int p = t & 1;
    const char* aK0 = &lds[p][0][0][0];
    const char* aK1 = &lds[p][0][1][0];
    const char* bK0 = &lds[p][1][0][0];
    const char* bK1 = &lds[p][1][1][0];
    bf16x8 aR[4], bR[4];
    // ---- P1: kk0, m-half 0 -> acc[0..3]; stage A(t+1,kk1) -> buf p^1
#pragma unroll
    for (int i = 0; i < 4; i++) aR[i] = *(const bf16x8*)(aK0 + aOff + i * 1024);
#pragma unroll
    for (int i = 0; i < 4; i++) bR[i] = *(const bf16x8*)(bK0 + bOff + i * 1024);
    if (t + 1 < ntk) stageA(p ^ 1, t + 1, 1);
    __builtin_amdgcn_s_barrier();
    asm volatile("s_waitcnt lgkmcnt(0)" ::: "memory");
    __builtin_amdgcn_s_setprio(1);
    MFMA_Q(0)
    __builtin_amdgcn_s_setprio(0);
    __builtin_amdgcn_s_barrier();
    // ---- P2: kk0, m-half 1 -> acc[4..7]; stage B(t+1,kk1); drain (t,kk1)
#pragma unroll
    for (int i = 0; i < 4; i++) aR[i] = *(const bf16x8*)(aK0 + aOff + (i + 4) * 1024);
    if (t + 1 < ntk) {
      stageB(p ^ 1, t + 1, 1);
      asm volatile("s_waitcnt vmcnt(8)" ::: "memory");
    } else {
      asm volatile("s_waitcnt vmcnt(0)" ::: "memory");
    }
    __builtin_amdgcn_s_barrier();
    asm volatile("s_waitcnt lgkmcnt(0)" ::: "memory");
    __builtin_amdgcn_s_setprio(1);
    MFMA_Q(1)
    __builtin_amdgcn_s_setprio(0);
    __builtin_amdgcn_s_barrier();
    // ---- P3: kk1, m-half 0 -> acc[0..3]; stage A(t+2,kk0) -> buf p
#pragma unroll
    for (int i = 0; i < 4; i++) aR[i] = *(const bf16x8*)(aK1 + aOff + i * 1024);
#pragma unroll
    for (int i = 0; i < 4; i++) bR[i] = *(const bf16x8*)(bK1 + bOff + i * 1024);
    if (t + 2 < ntk) stageA(p, t + 2, 0);
    __builtin_amdgcn_s_barrier();
    asm volatile("s_waitcnt lgkmcnt(0)" ::: "memory");
    __builtin_amdgcn_s_setprio(1);
    MFMA_Q(0)
    __builtin_amdgcn_s_setprio(0);
    __builtin_amdgcn_s_barrier();
    // ---- P4: kk1, m-half 1 -> acc[4..7]; stage B(t+2,kk0); drain (t+1,kk0)
#pragma unroll
    for (int i = 0; i < 4; i++) aR[i] = *(const bf16x8*)(aK1 + aOff + (i + 4) * 1024);
    if (t + 2 < ntk) {
      stageB(p, t + 2, 0);
      asm volatile("s_waitcnt vmcnt(8)" ::: "memory");
    } else if (t + 1 < ntk) {
      asm volatile("s_waitcnt vmcnt(4)" ::: "memory");
    }
    __builtin_amdgcn_s_barrier();
    asm volatile("s_waitcnt lgkmcnt(0)" ::: "memory");
    __builtin_amdgcn_s_setprio(1);
    MFMA_Q(1)
    __builtin_amdgcn_s_setprio(0);
    __builtin_amdgcn_s_barrier();
  }
#undef MFMA_Q

  const int r4 = (lane >> 4) * 4;
  if (PHASE == 1) {
    // fused gate: waves wc>=2 publish h2 (f32) via XOR-swizzled LDS, wc<2 combine.
    float* ldsF = (float*)&lds[0][0][0][0];      // 256 x 128 f32 = 128 KiB
    const int rbase = wr * 128 + r4;
    if (wc >= 2) {
      const int cb = (wc - 2) * 64;
#pragma unroll
      for (int mf = 0; mf < 8; mf++)
#pragma unroll
        for (int nf = 0; nf < 4; nf++) {
          int cc = cb + nf * 16 + lrow;
#pragma unroll
          for (int r = 0; r < 4; r++) {
            int rr = rbase + mf * 16 + r;
            ldsF[rr * 128 + (cc ^ (((rr >> 2) & 1) << 4))] = acc[mf][nf][r];
          }
        }
    }
    __syncthreads();
    if (wc < 2) {
      const int cb = wc * 64;
#pragma unroll
      for (int mf = 0; mf < 8; mf++) {
        int row0 = mt * 256 + wr * 128 + mf * 16 + r4;
#pragma unroll
        for (int nf = 0; nf < 4; nf++) {
          int cc = cb + nf * 16 + lrow;
          int col = nt * 128 + cc;
#pragma unroll
          for (int r = 0; r < 4; r++) {
            int rr = rbase + mf * 16 + r;
            float z1 = acc[mf][nf][r];
            float z2 = ldsF[rr * 128 + (cc ^ (((rr >> 2) & 1) << 4))];
            float gv = z1 / (1.f + __expf(-z1)) * z2;
            O[(size_t)(row0 + r) * ldo + col] = f2bf(gv);
          }
        }
      }
    }
  } else {
    const int rowb = mt * 256 + wr * 128;
    const int colb = nt * 256 + wc * 64;
    if (z < 2) {
      // shared proj: accumulate into y (pre-zeroed) with f32 atomics
#pragma unroll
      for (int mf = 0; mf < 8; mf++) {
        int row0 = rowb + mf * 16 + r4;
#pragma unroll
        for (int r = 0; r < 4; r++) {
          float* yrow = Of + (size_t)(row0 + r) * CDIM;
#pragma unroll
          for (int nf = 0; nf < 4; nf++)
            atomicAdd(yrow + colb + nf * 16 + lrow, acc[mf][nf][r]);
        }
      }
    } else {
      // expert proj: y[token] += w_slot * acc, guarded to live rows
#pragma unroll
      for (int mf = 0; mf < 8; mf++) {
        int row0 = rowb + mf * 16 + r4;
#pragma unroll
        for (int r = 0; r < 4; r++) {
          int s = row0 + r;
          if (s >= cnt) continue;
          int tok = lst[s];
          float w = wsl[s];
          float* yrow = yout + (size_t)tok * CDIM;
#pragma unroll
          for (int nf = 0; nf < 4; nf++)
            atomicAdd(yrow + colb + nf * 16 + lrow, w * acc[mf][nf][r]);
        }
      }
    }
  }
}

extern "C" void kernel_launch(void* const* d_in, const int* in_sizes, int n_in,
                              void* d_out, int out_size, void* d_ws, size_t ws_size,
                              hipStream_t stream) {
  const float* x   = (const float*)d_in[0];
  const float* gw  = (const float*)d_in[1];
  const float* w1  = (const float*)d_in[2];
  const float* w2  = (const float*)d_in[3];
  const float* w3  = (const float*)d_in[4];
  const float* sw1 = (const float*)d_in[5];
  const float* sw2 = (const float*)d_in[6];
  const float* sw3 = (const float*)d_in[7];
  float* y = (float*)d_out;

  char* ws = (char*)d_ws;
  size_t off = 0;
  auto alloc = [&](size_t b) -> void* {
    void* p = ws + off;
    off += (b + 255) & ~(size_t)255;
    return p;
  };
  unsigned short* xb    = (unsigned short*)alloc((size_t)N_TOK * CDIM * 2);
  unsigned short* wcat  = (unsigned short*)alloc((size_t)NEXP * ICAT * CDIM * 2);
  unsigned short* w3b   = (unsigned short*)alloc((size_t)NEXP * CDIM * IDIM * 2);
  unsigned short* swcat = (unsigned short*)alloc((size_t)SCAT * CDIM * 2);
  unsigned short* sw3b  = (unsigned short*)alloc((size_t)CDIM * ISDIM * 2);
  unsigned short* hs    = (unsigned short*)alloc((size_t)N_TOK * ISDIM * 2);
  unsigned short* he    = (unsigned short*)alloc((size_t)NEXP * CAP * IDIM * 2);
  int*   counts  = (int*)alloc(NEXP * 4);
  int*   list    = (int*)alloc((size_t)NEXP * CAP * 4);
  float* wslot   = (float*)alloc((size_t)NEXP * CAP * 4);

  hipMemsetAsync(counts, 0, NEXP * 4, stream);
  hipMemsetAsync(y, 0, (size_t)N_TOK * CDIM * 4, stream);   // atomic target
  routing_kernel<<<N_TOK, 64, 0, stream>>>(x, gw, counts, list, wslot);

  cvt_all<<<46336, 256, 0, stream>>>(x, w1, w2, w3, sw1, sw2, sw3,
                                     xb, wcat, w3b, swcat, sw3b);

  // fc GEMM with fused silu-gate epilogue
  moe_gemm<1><<<dim3(88, 1, 12), 512, 0, stream>>>(
      xb, swcat, wcat, hs, he, hs, sw3b, he, w3b, y, wslot, list, counts);

  // proj GEMM: z 0..1 shared (K=2816), z 2..9 experts (K=1408);
  // epilogue atomically accumulates into y (no eo/ysf/combine)
  moe_gemm<2><<<dim3(64, 1, 10), 512, 0, stream>>>(
      xb, swcat, wcat, hs, he, hs, sw3b, he, w3b, y, wslot, list, counts);
}

// Round 17
// 590.227 us; speedup vs baseline: 1.0437x; 1.0437x over previous
//
#include <hip/hip_runtime.h>
#include <stdint.h>

#define N_TOK 4096
#define CDIM  2048
#define NEXP  8
#define IDIM  1408
#define ISDIM 2816
#define CAP   2048
#define ICAT  2816   // interleaved [w1;w2] rows per expert (128-row groups)
#define SCAT  5632   // interleaved [sw1;sw2] rows (2 col-half sections)

typedef __attribute__((ext_vector_type(8))) short bf16x8;
typedef __attribute__((ext_vector_type(4))) float f32x4;

#define GLOAD16(gp, lp) __builtin_amdgcn_global_load_lds( \
    (const __attribute__((address_space(1))) void*)(gp),  \
    (__attribute__((address_space(3))) void*)(lp), 16, 0, 0)

__device__ __forceinline__ unsigned short f2bf(float f) {
  union { float f; unsigned u; } c; c.f = f;
  return (unsigned short)((c.u + 0x7FFFu + ((c.u >> 16) & 1u)) >> 16);
}
__device__ __forceinline__ float bf2f(unsigned short h) {
  union { unsigned u; float f; } c; c.u = (unsigned)h << 16;
  return c.f;
}

__device__ __forceinline__ int xcd_swizzle(int orig, int nwg) {
  int q = nwg >> 3, r = nwg & 7;
  int xcd = orig & 7, idx = orig >> 3;
  return (xcd < r ? xcd * (q + 1) : r * (q + 1) + (xcd - r) * q) + idx;
}

// ---------------- single fused fp32 -> bf16 convert, all tensors ----------------
__global__ __launch_bounds__(256) void cvt_all(
    const float* __restrict__ x, const float* __restrict__ w1,
    const float* __restrict__ w2, const float* __restrict__ w3,
    const float* __restrict__ sw1, const float* __restrict__ sw2,
    const float* __restrict__ sw3,
    unsigned short* __restrict__ xb, unsigned short* __restrict__ wcat,
    unsigned short* __restrict__ w3b, unsigned short* __restrict__ swcat,
    unsigned short* __restrict__ sw3b) {
  const int b = blockIdx.x;
  const int t = threadIdx.x;
  const float* src;
  unsigned short* dst;
  if (b < 4096) {
    src = x + (size_t)b * 2048;  dst = xb + (size_t)b * 2048;
  } else if (b < 15360) {
    size_t o = (size_t)(b - 4096) * 2048;  src = w3 + o;  dst = w3b + o;
  } else if (b < 18176) {
    size_t o = (size_t)(b - 15360) * 2048; src = sw3 + o; dst = sw3b + o;
  } else if (b < 40704) {
    int g = b - 18176;
    int e = g / 2816, r = g - e * 2816;
    int dr;
    if (r < 1408) { src = w1 + ((size_t)e * 1408 + r) * 2048; dr = (r >> 7) * 256 + (r & 127); }
    else { int r2 = r - 1408; src = w2 + ((size_t)e * 1408 + r2) * 2048; dr = (r2 >> 7) * 256 + 128 + (r2 & 127); }
    dst = wcat + ((size_t)e * ICAT + dr) * 2048;
  } else {
    int g = b - 40704;
    int dr;
    if (g < 2816) {
      int zn = g >= 1408, rr = g - zn * 1408;
      src = sw1 + (size_t)g * 2048;
      dr = zn * 2816 + (rr >> 7) * 256 + (rr & 127);
    } else {
      int r = g - 2816;
      int zn = r >= 1408, rr = r - zn * 1408;
      src = sw2 + (size_t)r * 2048;
      dr = zn * 2816 + (rr >> 7) * 256 + 128 + (rr & 127);
    }
    dst = swcat + (size_t)dr * 2048;
  }
  size_t i = (size_t)t * 8;
  float4 v0 = *(const float4*)(src + i);
  float4 v1 = *(const float4*)(src + i + 4);
  bf16x8 o;
  o[0] = (short)f2bf(v0.x); o[1] = (short)f2bf(v0.y);
  o[2] = (short)f2bf(v0.z); o[3] = (short)f2bf(v0.w);
  o[4] = (short)f2bf(v1.x); o[5] = (short)f2bf(v1.y);
  o[6] = (short)f2bf(v1.z); o[7] = (short)f2bf(v1.w);
  *(bf16x8*)(dst + i) = o;
}

// ---------------- routing ----------------
__global__ __launch_bounds__(64) void routing_kernel(
    const float* __restrict__ x, const float* __restrict__ gw,
    int* __restrict__ counts, int* __restrict__ list,
    int* __restrict__ slot_of, float* __restrict__ wts) {
  const int n = blockIdx.x;
  const int lane = threadIdx.x;
  const float* xr = x + (size_t)n * CDIM;
  float s[NEXP];
#pragma unroll
  for (int e = 0; e < NEXP; e++) s[e] = 0.f;
  for (int c = lane; c < CDIM; c += 64) {
    float xv = xr[c];
#pragma unroll
    for (int e = 0; e < NEXP; e++) s[e] += xv * gw[e * CDIM + c];
  }
#pragma unroll
  for (int e = 0; e < NEXP; e++) {
    float v = s[e];
    for (int o = 32; o > 0; o >>= 1) v += __shfl_down(v, o);
    s[e] = v;
  }
  if (lane == 0) {
    float mx = s[0];
#pragma unroll
    for (int e = 1; e < NEXP; e++) mx = fmaxf(mx, s[e]);
    float p[NEXP], sum = 0.f;
#pragma unroll
    for (int e = 0; e < NEXP; e++) { p[e] = __expf(s[e] - mx); sum += p[e]; }
    int i0 = 0;
#pragma unroll
    for (int e = 1; e < NEXP; e++) if (p[e] > p[i0]) i0 = e;
    int i1 = (i0 == 0) ? 1 : 0;
#pragma unroll
    for (int e = 0; e < NEXP; e++) if (e != i0 && p[e] > p[i1]) i1 = e;
    float inv = 1.f / sum;
    int s0 = atomicAdd(&counts[i0], 1);
    int s1 = atomicAdd(&counts[i1], 1);
    if (s0 < CAP) list[i0 * CAP + s0] = n; else s0 = 0;
    if (s1 < CAP) list[i1 * CAP + s1] = n; else s1 = 0;
    slot_of[n * 2]     = i0 * CAP + s0;
    slot_of[n * 2 + 1] = i1 * CAP + s1;
    wts[n * 2]     = p[i0] * inv;
    wts[n * 2 + 1] = p[i1] * inv;
  }
}

// ---------------- unified 8-phase deep-pipelined GEMM: Out = A @ B^T ----------------
// 256x256 tile, BK=64 (2 K-halves of 64B/row), 512 threads (8 waves, 2M x 4N).
// Best-measured config (R8/R15, 591us): 2 gloads per phase (stageA/stageB split),
// ledger-exact vmcnt(8)/(4)/(0); T2 both-sides swizzle; setprio around MFMA;
// m225 accumulator recipe; epilogue h2-exchange XOR-swizzled (conflict-free).
template <int PHASE>
__global__ __launch_bounds__(512) void moe_gemm(
    const unsigned short* __restrict__ xb,
    const unsigned short* __restrict__ swcat,
    const unsigned short* __restrict__ wcat,
    unsigned short* __restrict__ hs_out,
    unsigned short* __restrict__ he_out,
    const unsigned short* __restrict__ hs,
    const unsigned short* __restrict__ sw3b,
    const unsigned short* __restrict__ he,
    const unsigned short* __restrict__ w3b,
    float* __restrict__ ysf,
    unsigned short* __restrict__ eo,
    const int* __restrict__ list,
    const int* __restrict__ counts) {
  const int z = blockIdx.z;
  const unsigned short *A, *B;
  unsigned short* O = nullptr;
  float* Of = nullptr;
  int Ka, ldo;
  int cnt = 1 << 30;
  const int* lst = nullptr;
  int Mt, Nt;
  bool gath = false;
  if (PHASE == 1) {
    Mt = 8; Nt = 11; Ka = CDIM;
    if (z < 4) {
      int zm = z >> 1, zn = z & 1;
      A = xb + (size_t)zm * 2048 * CDIM;
      B = swcat + (size_t)zn * 2816 * CDIM;
      O = hs_out + (size_t)zm * 2048 * ISDIM + (size_t)zn * 1408;
      ldo = ISDIM;
    } else {
      int e = z - 4;
      cnt = counts[e]; if (cnt > CAP) cnt = CAP;
      lst = list + e * CAP;
      gath = true;
      A = xb;
      B = wcat + (size_t)e * ICAT * CDIM;
      O = he_out + (size_t)e * CAP * IDIM;
      ldo = IDIM;
    }
  } else {
    Mt = 8; Nt = 8;
    if (z < 2) {
      Ka = ISDIM;
      A = hs + (size_t)z * 2048 * ISDIM;
      B = sw3b;
      Of = ysf + (size_t)z * 2048 * CDIM;
      ldo = CDIM;
    } else {
      int e = z - 2;
      cnt = counts[e]; if (cnt > CAP) cnt = CAP;
      Ka = IDIM;
      A = he + (size_t)e * CAP * IDIM;
      B = w3b + (size_t)e * CDIM * IDIM;
      O = eo + (size_t)e * CAP * CDIM;
      ldo = CDIM;
    }
  }
  const int wg = xcd_swizzle(blockIdx.x, Mt * Nt);
  const int mt = wg % Mt, nt = wg / Mt;
  if (mt * 256 >= cnt) return;

  __shared__ __align__(16) char lds[2][2][2][16384]; // [buf][A|B][kk][256x64B]

  const int tid = threadIdx.x;
  const int srow = tid >> 2;
  const int c16  = (tid & 3) << 4;
  const int scol = c16 ^ (((srow >> 1) & 3) << 4);
  const char* aS[2];
  const char* bS[2];
#pragma unroll
  for (int j = 0; j < 2; j++) {
    int ar = mt * 256 + j * 128 + srow;
    if (PHASE == 1 && gath) ar = (ar < cnt) ? lst[ar] : lst[0];
    aS[j] = (const char*)A + (size_t)ar * Ka * 2 + scol;
    int br = nt * 256 + j * 128 + srow;
    bS[j] = (const char*)B + (size_t)br * Ka * 2 + scol;
  }
  auto stageA = [&](int buf, int kt, int h) {
    size_t kb = (size_t)kt * 128 + (size_t)(h << 6);
    char* aD = &lds[buf][0][h][0] + tid * 16;
    GLOAD16(aS[0] + kb, aD);
    GLOAD16(aS[1] + kb, aD + 8192);
  };
  auto stageB = [&](int buf, int kt, int h) {
    size_t kb = (size_t)kt * 128 + (size_t)(h << 6);
    char* bD = &lds[buf][1][h][0] + tid * 16;
    GLOAD16(bS[0] + kb, bD);
    GLOAD16(bS[1] + kb, bD + 8192);
  };

  const int lane = tid & 63, wid = tid >> 6;
  const int wr = wid >> 2, wc = wid & 3;   // 2 x 4 wave grid, per-wave 128x64
  const int lrow = lane & 15;
  const int klane = (lane >> 4) << 4;
  const int rsw = ((lrow >> 1) & 3) << 4;
  const int aOff = (wr * 128 + lrow) * 64 + (klane ^ rsw);
  const int bOff = (wc * 64 + lrow) * 64 + (klane ^ rsw);

  f32x4 acc[8][4];
#pragma unroll
  for (int mf = 0; mf < 8; mf++)
#pragma unroll
    for (int nf = 0; nf < 4; nf++) acc[mf][nf] = (f32x4){0.f, 0.f, 0.f, 0.f};

  // prologue: (0,kk0),(0,kk1),(1,kk0) staged; drain (0,kk0) [8 newer]
  stageA(0, 0, 0); stageB(0, 0, 0);
  stageA(0, 0, 1); stageB(0, 0, 1);
  stageA(1, 1, 0); stageB(1, 1, 0);
  asm volatile("s_waitcnt vmcnt(8)" ::: "memory");
  __builtin_amdgcn_s_barrier();

#define MFMA_Q(MB)                                                             \
  _Pragma("unroll")                                                            \
  for (int nf = 0; nf < 4; nf++)                                               \
    _Pragma("unroll")                                                          \
    for (int m = 0; m < 4; m++)                                                \
      acc[(MB) * 4 + m][nf] = __builtin_amdgcn_mfma_f32_16x16x32_bf16(         \
          aR[m], bR[nf], acc[(MB) * 4 + m][nf], 0, 0, 0);

  const int ntk = Ka >> 6;
  for (int t = 0; t < ntk; t++) {
    const int p = t & 1;
    const char* aK0 = &lds[p][0][0][0];
    const char* aK1 = &lds[p][0][1][0];
    const char* bK0 = &lds[p][1][0][0];
    const char* bK1 = &lds[p][1][1][0];
    bf16x8 aR[4], bR[4];
    // ---- P1: kk0, m-half 0 -> acc[0..3]; stage A(t+1,kk1) -> buf p^1
#pragma unroll
    for (int i = 0; i < 4; i++) aR[i] = *(const bf16x8*)(aK0 + aOff + i * 1024);
#pragma unroll
    for (int i = 0; i < 4; i++) bR[i] = *(const bf16x8*)(bK0 + bOff + i * 1024);
    if (t + 1 < ntk) stageA(p ^ 1, t + 1, 1);
    __builtin_amdgcn_s_barrier();
    asm volatile("s_waitcnt lgkmcnt(0)" ::: "memory");
    __builtin_amdgcn_s_setprio(1);
    MFMA_Q(0)
    __builtin_amdgcn_s_setprio(0);
    __builtin_amdgcn_s_barrier();
    // ---- P2: kk0, m-half 1 -> acc[4..7]; stage B(t+1,kk1); drain (t,kk1)
#pragma unroll
    for (int i = 0; i < 4; i++) aR[i] = *(const bf16x8*)(aK0 + aOff + (i + 4) * 1024);
    if (t + 1 < ntk) {
      stageB(p ^ 1, t + 1, 1);
      asm volatile("s_waitcnt vmcnt(8)" ::: "memory");
    } else {
      asm volatile("s_waitcnt vmcnt(0)" ::: "memory");
    }
    __builtin_amdgcn_s_barrier();
    asm volatile("s_waitcnt lgkmcnt(0)" ::: "memory");
    __builtin_amdgcn_s_setprio(1);
    MFMA_Q(1)
    __builtin_amdgcn_s_setprio(0);
    __builtin_amdgcn_s_barrier();
    // ---- P3: kk1, m-half 0 -> acc[0..3]; stage A(t+2,kk0) -> buf p
#pragma unroll
    for (int i = 0; i < 4; i++) aR[i] = *(const bf16x8*)(aK1 + aOff + i * 1024);
#pragma unroll
    for (int i = 0; i < 4; i++) bR[i] = *(const bf16x8*)(bK1 + bOff + i * 1024);
    if (t + 2 < ntk) stageA(p, t + 2, 0);
    __builtin_amdgcn_s_barrier();
    asm volatile("s_waitcnt lgkmcnt(0)" ::: "memory");
    __builtin_amdgcn_s_setprio(1);
    MFMA_Q(0)
    __builtin_amdgcn_s_setprio(0);
    __builtin_amdgcn_s_barrier();
    // ---- P4: kk1, m-half 1 -> acc[4..7]; stage B(t+2,kk0); drain (t+1,kk0)
#pragma unroll
    for (int i = 0; i < 4; i++) aR[i] = *(const bf16x8*)(aK1 + aOff + (i + 4) * 1024);
    if (t + 2 < ntk) {
      stageB(p, t + 2, 0);
      asm volatile("s_waitcnt vmcnt(8)" ::: "memory");
    } else if (t + 1 < ntk) {
      asm volatile("s_waitcnt vmcnt(4)" ::: "memory");
    }
    __builtin_amdgcn_s_barrier();
    asm volatile("s_waitcnt lgkmcnt(0)" ::: "memory");
    __builtin_amdgcn_s_setprio(1);
    MFMA_Q(1)
    __builtin_amdgcn_s_setprio(0);
    __builtin_amdgcn_s_barrier();
  }
#undef MFMA_Q

  const int r4 = (lane >> 4) * 4;
  if (PHASE == 1) {
    // fused gate: waves wc>=2 publish h2 (f32) via XOR-swizzled LDS, wc<2 combine.
    float* ldsF = (float*)&lds[0][0][0][0];      // 256 x 128 f32 = 128 KiB
    const int rbase = wr * 128 + r4;
    if (wc >= 2) {
      const int cb = (wc - 2) * 64;
#pragma unroll
      for (int mf = 0; mf < 8; mf++)
#pragma unroll
        for (int nf = 0; nf < 4; nf++) {
          int cc = cb + nf * 16 + lrow;
#pragma unroll
          for (int r = 0; r < 4; r++) {
            int rr = rbase + mf * 16 + r;
            ldsF[rr * 128 + (cc ^ (((rr >> 2) & 1) << 4))] = acc[mf][nf][r];
          }
        }
    }
    __syncthreads();
    if (wc < 2) {
      const int cb = wc * 64;
#pragma unroll
      for (int mf = 0; mf < 8; mf++) {
        int row0 = mt * 256 + wr * 128 + mf * 16 + r4;
#pragma unroll
        for (int nf = 0; nf < 4; nf++) {
          int cc = cb + nf * 16 + lrow;
          int col = nt * 128 + cc;
#pragma unroll
          for (int r = 0; r < 4; r++) {
            int rr = rbase + mf * 16 + r;
            float z1 = acc[mf][nf][r];
            float z2 = ldsF[rr * 128 + (cc ^ (((rr >> 2) & 1) << 4))];
            float gv = z1 / (1.f + __expf(-z1)) * z2;
            O[(size_t)(row0 + r) * ldo + col] = f2bf(gv);
          }
        }
      }
    }
  } else {
    const int rowb = mt * 256 + wr * 128;
    const int colb = nt * 256 + wc * 64;
#pragma unroll
    for (int mf = 0; mf < 8; mf++) {
      int row0 = rowb + mf * 16 + r4;
#pragma unroll
      for (int nf = 0; nf < 4; nf++) {
        int col = colb + nf * 16 + lrow;
#pragma unroll
        for (int r = 0; r < 4; r++) {
          if (z < 2)
            Of[(size_t)(row0 + r) * ldo + col] = acc[mf][nf][r];
          else
            O[(size_t)(row0 + r) * ldo + col] = f2bf(acc[mf][nf][r]);
        }
      }
    }
  }
}

// ---------------- combine: y = ys + sum_k w_k * eo[slot_k] ----------------
__global__ __launch_bounds__(256) void combine_kernel(
    float* __restrict__ y, const float* __restrict__ ysf,
    const unsigned short* __restrict__ eo,
    const int* __restrict__ slot_of, const float* __restrict__ wts) {
  int idx = blockIdx.x * 256 + threadIdx.x;
  int n = idx >> 9;
  int c = (idx & 511) * 4;
  float4 v = *(const float4*)(ysf + (size_t)n * CDIM + c);
#pragma unroll
  for (int k = 0; k < 2; k++) {
    int slot = slot_of[n * 2 + k];
    float w = wts[n * 2 + k];
    ushort4 h = *(const ushort4*)(eo + (size_t)slot * CDIM + c);
    v.x += w * bf2f(h.x);
    v.y += w * bf2f(h.y);
    v.z += w * bf2f(h.z);
    v.w += w * bf2f(h.w);
  }
  *(float4*)(y + (size_t)n * CDIM + c) = v;
}

extern "C" void kernel_launch(void* const* d_in, const int* in_sizes, int n_in,
                              void* d_out, int out_size, void* d_ws, size_t ws_size,
                              hipStream_t stream) {
  const float* x   = (const float*)d_in[0];
  const float* gw  = (const float*)d_in[1];
  const float* w1  = (const float*)d_in[2];
  const float* w2  = (const float*)d_in[3];
  const float* w3  = (const float*)d_in[4];
  const float* sw1 = (const float*)d_in[5];
  const float* sw2 = (const float*)d_in[6];
  const float* sw3 = (const float*)d_in[7];
  float* y = (float*)d_out;

  char* ws = (char*)d_ws;
  size_t off = 0;
  auto alloc = [&](size_t b) -> void* {
    void* p = ws + off;
    off += (b + 255) & ~(size_t)255;
    return p;
  };
  unsigned short* xb    = (unsigned short*)alloc((size_t)N_TOK * CDIM * 2);
  unsigned short* wcat  = (unsigned short*)alloc((size_t)NEXP * ICAT * CDIM * 2);
  unsigned short* w3b   = (unsigned short*)alloc((size_t)NEXP * CDIM * IDIM * 2);
  unsigned short* swcat = (unsigned short*)alloc((size_t)SCAT * CDIM * 2);
  unsigned short* sw3b  = (unsigned short*)alloc((size_t)CDIM * ISDIM * 2);
  unsigned short* hs    = (unsigned short*)alloc((size_t)N_TOK * ISDIM * 2);
  unsigned short* he    = (unsigned short*)alloc((size_t)NEXP * CAP * IDIM * 2);
  float*          ysf   = (float*)alloc((size_t)N_TOK * CDIM * 4);
  int*   counts  = (int*)alloc(NEXP * 4);
  int*   list    = (int*)alloc((size_t)NEXP * CAP * 4);
  int*   slot_of = (int*)alloc((size_t)N_TOK * 2 * 4);
  float* wtsb    = (float*)alloc((size_t)N_TOK * 2 * 4);
  // alias: eo reuses wcat (dead after fc GEMM)
  unsigned short* eoB = wcat;

  hipMemsetAsync(counts, 0, NEXP * 4, stream);
  routing_kernel<<<N_TOK, 64, 0, stream>>>(x, gw, counts, list, slot_of, wtsb);

  cvt_all<<<46336, 256, 0, stream>>>(x, w1, w2, w3, sw1, sw2, sw3,
                                     xb, wcat, w3b, swcat, sw3b);

  // fc GEMM with fused silu-gate epilogue
  moe_gemm<1><<<dim3(88, 1, 12), 512, 0, stream>>>(
      xb, swcat, wcat, hs, he, hs, sw3b, he, w3b, ysf, eoB, list, counts);

  // proj GEMM: z 0..1 shared (long K first), z 2..9 experts
  moe_gemm<2><<<dim3(64, 1, 10), 512, 0, stream>>>(
      xb, swcat, wcat, hs, he, hs, sw3b, he, w3b, ysf, eoB, list, counts);

  // combine
  combine_kernel<<<(N_TOK * (CDIM / 4)) / 256, 256, 0, stream>>>(y, ysf, eoB, slot_of, wtsb);
}

// Round 18
// 569.972 us; speedup vs baseline: 1.0808x; 1.0355x over previous
//
#include <hip/hip_runtime.h>
#include <stdint.h>

#define N_TOK 4096
#define CDIM  2048
#define NEXP  8
#define IDIM  1408
#define ISDIM 2816
#define CAP   2048
#define ICAT  2816   // interleaved [w1;w2] rows per expert (128-row groups)
#define SCAT  5632   // interleaved [sw1;sw2] rows (2 col-half sections)

typedef __attribute__((ext_vector_type(8))) short bf16x8;
typedef __attribute__((ext_vector_type(4))) float f32x4;

#define GLOAD16(gp, lp) __builtin_amdgcn_global_load_lds( \
    (const __attribute__((address_space(1))) void*)(gp),  \
    (__attribute__((address_space(3))) void*)(lp), 16, 0, 0)

__device__ __forceinline__ unsigned short f2bf(float f) {
  union { float f; unsigned u; } c; c.f = f;
  return (unsigned short)((c.u + 0x7FFFu + ((c.u >> 16) & 1u)) >> 16);
}
__device__ __forceinline__ float bf2f(unsigned short h) {
  union { unsigned u; float f; } c; c.u = (unsigned)h << 16;
  return c.f;
}

__device__ __forceinline__ int xcd_swizzle(int orig, int nwg) {
  int q = nwg >> 3, r = nwg & 7;
  int xcd = orig & 7, idx = orig >> 3;
  return (xcd < r ? xcd * (q + 1) : r * (q + 1) + (xcd - r) * q) + idx;
}

// ---------------- fused fp32 -> bf16 convert: fc-side tensors only ----------------
// (w3/sw3 conversion moved into the fc GEMM launch as z=12 — overlaps with compute)
__global__ __launch_bounds__(256) void cvt_all(
    const float* __restrict__ x, const float* __restrict__ w1,
    const float* __restrict__ w2,
    const float* __restrict__ sw1, const float* __restrict__ sw2,
    unsigned short* __restrict__ xb, unsigned short* __restrict__ wcat,
    unsigned short* __restrict__ swcat) {
  const int b = blockIdx.x;
  const int t = threadIdx.x;
  const float* src;
  unsigned short* dst;
  if (b < 4096) {
    src = x + (size_t)b * 2048;  dst = xb + (size_t)b * 2048;
  } else if (b < 26624) {
    int g = b - 4096;
    int e = g / 2816, r = g - e * 2816;
    int dr;
    if (r < 1408) { src = w1 + ((size_t)e * 1408 + r) * 2048; dr = (r >> 7) * 256 + (r & 127); }
    else { int r2 = r - 1408; src = w2 + ((size_t)e * 1408 + r2) * 2048; dr = (r2 >> 7) * 256 + 128 + (r2 & 127); }
    dst = wcat + ((size_t)e * ICAT + dr) * 2048;
  } else {
    int g = b - 26624;
    int dr;
    if (g < 2816) {
      int zn = g >= 1408, rr = g - zn * 1408;
      src = sw1 + (size_t)g * 2048;
      dr = zn * 2816 + (rr >> 7) * 256 + (rr & 127);
    } else {
      int r = g - 2816;
      int zn = r >= 1408, rr = r - zn * 1408;
      src = sw2 + (size_t)r * 2048;
      dr = zn * 2816 + (rr >> 7) * 256 + 128 + (rr & 127);
    }
    dst = swcat + (size_t)dr * 2048;
  }
  size_t i = (size_t)t * 8;
  float4 v0 = *(const float4*)(src + i);
  float4 v1 = *(const float4*)(src + i + 4);
  bf16x8 o;
  o[0] = (short)f2bf(v0.x); o[1] = (short)f2bf(v0.y);
  o[2] = (short)f2bf(v0.z); o[3] = (short)f2bf(v0.w);
  o[4] = (short)f2bf(v1.x); o[5] = (short)f2bf(v1.y);
  o[6] = (short)f2bf(v1.z); o[7] = (short)f2bf(v1.w);
  *(bf16x8*)(dst + i) = o;
}

// ---------------- routing ----------------
__global__ __launch_bounds__(64) void routing_kernel(
    const float* __restrict__ x, const float* __restrict__ gw,
    int* __restrict__ counts, int* __restrict__ list,
    int* __restrict__ slot_of, float* __restrict__ wts) {
  const int n = blockIdx.x;
  const int lane = threadIdx.x;
  const float* xr = x + (size_t)n * CDIM;
  float s[NEXP];
#pragma unroll
  for (int e = 0; e < NEXP; e++) s[e] = 0.f;
  for (int c = lane; c < CDIM; c += 64) {
    float xv = xr[c];
#pragma unroll
    for (int e = 0; e < NEXP; e++) s[e] += xv * gw[e * CDIM + c];
  }
#pragma unroll
  for (int e = 0; e < NEXP; e++) {
    float v = s[e];
    for (int o = 32; o > 0; o >>= 1) v += __shfl_down(v, o);
    s[e] = v;
  }
  if (lane == 0) {
    float mx = s[0];
#pragma unroll
    for (int e = 1; e < NEXP; e++) mx = fmaxf(mx, s[e]);
    float p[NEXP], sum = 0.f;
#pragma unroll
    for (int e = 0; e < NEXP; e++) { p[e] = __expf(s[e] - mx); sum += p[e]; }
    int i0 = 0;
#pragma unroll
    for (int e = 1; e < NEXP; e++) if (p[e] > p[i0]) i0 = e;
    int i1 = (i0 == 0) ? 1 : 0;
#pragma unroll
    for (int e = 0; e < NEXP; e++) if (e != i0 && p[e] > p[i1]) i1 = e;
    float inv = 1.f / sum;
    int s0 = atomicAdd(&counts[i0], 1);
    int s1 = atomicAdd(&counts[i1], 1);
    if (s0 < CAP) list[i0 * CAP + s0] = n; else s0 = 0;
    if (s1 < CAP) list[i1 * CAP + s1] = n; else s1 = 0;
    slot_of[n * 2]     = i0 * CAP + s0;
    slot_of[n * 2 + 1] = i1 * CAP + s1;
    wts[n * 2]     = p[i0] * inv;
    wts[n * 2 + 1] = p[i1] * inv;
  }
}

// ---------------- unified 8-phase deep-pipelined GEMM: Out = A @ B^T ----------------
// 256x256 tile, BK=64 (2 K-halves of 64B/row), 512 threads (8 waves, 2M x 4N).
// Best-measured core (R8/R15, ~591us): 2 gloads per phase (stageA/stageB split),
// ledger-exact vmcnt(8)/(4)/(0); T2 both-sides swizzle; setprio around MFMA;
// m225 accumulator recipe; fc epilogue h2-exchange XOR-swizzled (conflict-free).
// R18: fc launch carries z=12 = grid-stride w3/sw3 fp32->bf16 convert, which
// co-schedules with the compute-bound GEMM blocks (fc is at 16% HBM) and thus
// hides the proj-weight convert; proj (next launch, same stream) sees it done.
template <int PHASE>
__global__ __launch_bounds__(512) void moe_gemm(
    const unsigned short* __restrict__ xb,
    const unsigned short* __restrict__ swcat,
    const unsigned short* __restrict__ wcat,
    unsigned short* __restrict__ hs_out,
    unsigned short* __restrict__ he_out,
    const unsigned short* __restrict__ hs,
    const unsigned short* __restrict__ sw3b,
    const unsigned short* __restrict__ he,
    const unsigned short* __restrict__ w3b,
    float* __restrict__ ysf,
    unsigned short* __restrict__ eo,
    const int* __restrict__ list,
    const int* __restrict__ counts,
    const float* __restrict__ w3f,
    const float* __restrict__ sw3f,
    unsigned short* __restrict__ w3b_mut,
    unsigned short* __restrict__ sw3b_mut) {
  const int z = blockIdx.z;
  if (PHASE == 1 && z == 12) {
    // overlapped convert: w3 -> w3b, sw3 -> sw3b (grid-stride, 88 blocks)
    const size_t W3E  = (size_t)NEXP * CDIM * IDIM;          // 23,068,672
    const size_t TOTE = W3E + (size_t)CDIM * ISDIM;          // 28,835,840
    const size_t stride = (size_t)88 * 512 * 8;
    for (size_t i = ((size_t)blockIdx.x * 512 + threadIdx.x) * 8; i < TOTE; i += stride) {
      const float* s;
      unsigned short* d;
      if (i < W3E) { s = w3f + i; d = w3b_mut + i; }
      else         { s = sw3f + (i - W3E); d = sw3b_mut + (i - W3E); }
      float4 v0 = *(const float4*)s;
      float4 v1 = *(const float4*)(s + 4);
      bf16x8 o;
      o[0] = (short)f2bf(v0.x); o[1] = (short)f2bf(v0.y);
      o[2] = (short)f2bf(v0.z); o[3] = (short)f2bf(v0.w);
      o[4] = (short)f2bf(v1.x); o[5] = (short)f2bf(v1.y);
      o[6] = (short)f2bf(v1.z); o[7] = (short)f2bf(v1.w);
      *(bf16x8*)d = o;
    }
    return;
  }
  const unsigned short *A, *B;
  unsigned short* O = nullptr;
  float* Of = nullptr;
  int Ka, ldo;
  int cnt = 1 << 30;
  const int* lst = nullptr;
  int Mt, Nt;
  bool gath = false;
  if (PHASE == 1) {
    Mt = 8; Nt = 11; Ka = CDIM;
    if (z < 4) {
      int zm = z >> 1, zn = z & 1;
      A = xb + (size_t)zm * 2048 * CDIM;
      B = swcat + (size_t)zn * 2816 * CDIM;
      O = hs_out + (size_t)zm * 2048 * ISDIM + (size_t)zn * 1408;
      ldo = ISDIM;
    } else {
      int e = z - 4;
      cnt = counts[e]; if (cnt > CAP) cnt = CAP;
      lst = list + e * CAP;
      gath = true;
      A = xb;
      B = wcat + (size_t)e * ICAT * CDIM;
      O = he_out + (size_t)e * CAP * IDIM;
      ldo = IDIM;
    }
  } else {
    Mt = 8; Nt = 8;
    if (z < 2) {
      Ka = ISDIM;
      A = hs + (size_t)z * 2048 * ISDIM;
      B = sw3b;
      Of = ysf + (size_t)z * 2048 * CDIM;
      ldo = CDIM;
    } else {
      int e = z - 2;
      cnt = counts[e]; if (cnt > CAP) cnt = CAP;
      Ka = IDIM;
      A = he + (size_t)e * CAP * IDIM;
      B = w3b + (size_t)e * CDIM * IDIM;
      O = eo + (size_t)e * CAP * CDIM;
      ldo = CDIM;
    }
  }
  const int wg = xcd_swizzle(blockIdx.x, Mt * Nt);
  const int mt = wg % Mt, nt = wg / Mt;
  if (mt * 256 >= cnt) return;

  __shared__ __align__(16) char lds[2][2][2][16384]; // [buf][A|B][kk][256x64B]

  const int tid = threadIdx.x;
  const int srow = tid >> 2;
  const int c16  = (tid & 3) << 4;
  const int scol = c16 ^ (((srow >> 1) & 3) << 4);
  const char* aS[2];
  const char* bS[2];
#pragma unroll
  for (int j = 0; j < 2; j++) {
    int ar = mt * 256 + j * 128 + srow;
    if (PHASE == 1 && gath) ar = (ar < cnt) ? lst[ar] : lst[0];
    aS[j] = (const char*)A + (size_t)ar * Ka * 2 + scol;
    int br = nt * 256 + j * 128 + srow;
    bS[j] = (const char*)B + (size_t)br * Ka * 2 + scol;
  }
  auto stageA = [&](int buf, int kt, int h) {
    size_t kb = (size_t)kt * 128 + (size_t)(h << 6);
    char* aD = &lds[buf][0][h][0] + tid * 16;
    GLOAD16(aS[0] + kb, aD);
    GLOAD16(aS[1] + kb, aD + 8192);
  };
  auto stageB = [&](int buf, int kt, int h) {
    size_t kb = (size_t)kt * 128 + (size_t)(h << 6);
    char* bD = &lds[buf][1][h][0] + tid * 16;
    GLOAD16(bS[0] + kb, bD);
    GLOAD16(bS[1] + kb, bD + 8192);
  };

  const int lane = tid & 63, wid = tid >> 6;
  const int wr = wid >> 2, wc = wid & 3;   // 2 x 4 wave grid, per-wave 128x64
  const int lrow = lane & 15;
  const int klane = (lane >> 4) << 4;
  const int rsw = ((lrow >> 1) & 3) << 4;
  const int aOff = (wr * 128 + lrow) * 64 + (klane ^ rsw);
  const int bOff = (wc * 64 + lrow) * 64 + (klane ^ rsw);

  f32x4 acc[8][4];
#pragma unroll
  for (int mf = 0; mf < 8; mf++)
#pragma unroll
    for (int nf = 0; nf < 4; nf++) acc[mf][nf] = (f32x4){0.f, 0.f, 0.f, 0.f};

  // prologue: (0,kk0),(0,kk1),(1,kk0) staged; drain (0,kk0) [8 newer]
  stageA(0, 0, 0); stageB(0, 0, 0);
  stageA(0, 0, 1); stageB(0, 0, 1);
  stageA(1, 1, 0); stageB(1, 1, 0);
  asm volatile("s_waitcnt vmcnt(8)" ::: "memory");
  __builtin_amdgcn_s_barrier();

#define MFMA_Q(MB)                                                             \
  _Pragma("unroll")                                                            \
  for (int nf = 0; nf < 4; nf++)                                               \
    _Pragma("unroll")                                                          \
    for (int m = 0; m < 4; m++)                                                \
      acc[(MB) * 4 + m][nf] = __builtin_amdgcn_mfma_f32_16x16x32_bf16(         \
          aR[m], bR[nf], acc[(MB) * 4 + m][nf], 0, 0, 0);

  const int ntk = Ka >> 6;
  for (int t = 0; t < ntk; t++) {
    const int p = t & 1;
    const char* aK0 = &lds[p][0][0][0];
    const char* aK1 = &lds[p][0][1][0];
    const char* bK0 = &lds[p][1][0][0];
    const char* bK1 = &lds[p][1][1][0];
    bf16x8 aR[4], bR[4];
    // ---- P1: kk0, m-half 0 -> acc[0..3]; stage A(t+1,kk1) -> buf p^1
#pragma unroll
    for (int i = 0; i < 4; i++) aR[i] = *(const bf16x8*)(aK0 + aOff + i * 1024);
#pragma unroll
    for (int i = 0; i < 4; i++) bR[i] = *(const bf16x8*)(bK0 + bOff + i * 1024);
    if (t + 1 < ntk) stageA(p ^ 1, t + 1, 1);
    __builtin_amdgcn_s_barrier();
    asm volatile("s_waitcnt lgkmcnt(0)" ::: "memory");
    __builtin_amdgcn_s_setprio(1);
    MFMA_Q(0)
    __builtin_amdgcn_s_setprio(0);
    __builtin_amdgcn_s_barrier();
    // ---- P2: kk0, m-half 1 -> acc[4..7]; stage B(t+1,kk1); drain (t,kk1)
#pragma unroll
    for (int i = 0; i < 4; i++) aR[i] = *(const bf16x8*)(aK0 + aOff + (i + 4) * 1024);
    if (t + 1 < ntk) {
      stageB(p ^ 1, t + 1, 1);
      asm volatile("s_waitcnt vmcnt(8)" ::: "memory");
    } else {
      asm volatile("s_waitcnt vmcnt(0)" ::: "memory");
    }
    __builtin_amdgcn_s_barrier();
    asm volatile("s_waitcnt lgkmcnt(0)" ::: "memory");
    __builtin_amdgcn_s_setprio(1);
    MFMA_Q(1)
    __builtin_amdgcn_s_setprio(0);
    __builtin_amdgcn_s_barrier();
    // ---- P3: kk1, m-half 0 -> acc[0..3]; stage A(t+2,kk0) -> buf p
#pragma unroll
    for (int i = 0; i < 4; i++) aR[i] = *(const bf16x8*)(aK1 + aOff + i * 1024);
#pragma unroll
    for (int i = 0; i < 4; i++) bR[i] = *(const bf16x8*)(bK1 + bOff + i * 1024);
    if (t + 2 < ntk) stageA(p, t + 2, 0);
    __builtin_amdgcn_s_barrier();
    asm volatile("s_waitcnt lgkmcnt(0)" ::: "memory");
    __builtin_amdgcn_s_setprio(1);
    MFMA_Q(0)
    __builtin_amdgcn_s_setprio(0);
    __builtin_amdgcn_s_barrier();
    // ---- P4: kk1, m-half 1 -> acc[4..7]; stage B(t+2,kk0); drain (t+1,kk0)
#pragma unroll
    for (int i = 0; i < 4; i++) aR[i] = *(const bf16x8*)(aK1 + aOff + (i + 4) * 1024);
    if (t + 2 < ntk) {
      stageB(p, t + 2, 0);
      asm volatile("s_waitcnt vmcnt(8)" ::: "memory");
    } else if (t + 1 < ntk) {
      asm volatile("s_waitcnt vmcnt(4)" ::: "memory");
    }
    __builtin_amdgcn_s_barrier();
    asm volatile("s_waitcnt lgkmcnt(0)" ::: "memory");
    __builtin_amdgcn_s_setprio(1);
    MFMA_Q(1)
    __builtin_amdgcn_s_setprio(0);
    __builtin_amdgcn_s_barrier();
  }
#undef MFMA_Q

  const int r4 = (lane >> 4) * 4;
  if (PHASE == 1) {
    // fused gate: waves wc>=2 publish h2 (f32) via XOR-swizzled LDS, wc<2 combine.
    float* ldsF = (float*)&lds[0][0][0][0];      // 256 x 128 f32 = 128 KiB
    const int rbase = wr * 128 + r4;
    if (wc >= 2) {
      const int cb = (wc - 2) * 64;
#pragma unroll
      for (int mf = 0; mf < 8; mf++)
#pragma unroll
        for (int nf = 0; nf < 4; nf++) {
          int cc = cb + nf * 16 + lrow;
#pragma unroll
          for (int r = 0; r < 4; r++) {
            int rr = rbase + mf * 16 + r;
            ldsF[rr * 128 + (cc ^ (((rr >> 2) & 1) << 4))] = acc[mf][nf][r];
          }
        }
    }
    __syncthreads();
    if (wc < 2) {
      const int cb = wc * 64;
#pragma unroll
      for (int mf = 0; mf < 8; mf++) {
        int row0 = mt * 256 + wr * 128 + mf * 16 + r4;
#pragma unroll
        for (int nf = 0; nf < 4; nf++) {
          int cc = cb + nf * 16 + lrow;
          int col = nt * 128 + cc;
#pragma unroll
          for (int r = 0; r < 4; r++) {
            int rr = rbase + mf * 16 + r;
            float z1 = acc[mf][nf][r];
            float z2 = ldsF[rr * 128 + (cc ^ (((rr >> 2) & 1) << 4))];
            float gv = z1 / (1.f + __expf(-z1)) * z2;
            O[(size_t)(row0 + r) * ldo + col] = f2bf(gv);
          }
        }
      }
    }
  } else {
    const int rowb = mt * 256 + wr * 128;
    const int colb = nt * 256 + wc * 64;
#pragma unroll
    for (int mf = 0; mf < 8; mf++) {
      int row0 = rowb + mf * 16 + r4;
#pragma unroll
      for (int nf = 0; nf < 4; nf++) {
        int col = colb + nf * 16 + lrow;
#pragma unroll
        for (int r = 0; r < 4; r++) {
          if (z < 2)
            Of[(size_t)(row0 + r) * ldo + col] = acc[mf][nf][r];
          else
            O[(size_t)(row0 + r) * ldo + col] = f2bf(acc[mf][nf][r]);
        }
      }
    }
  }
}

// ---------------- combine: y = ys + sum_k w_k * eo[slot_k] ----------------
__global__ __launch_bounds__(256) void combine_kernel(
    float* __restrict__ y, const float* __restrict__ ysf,
    const unsigned short* __restrict__ eo,
    const int* __restrict__ slot_of, const float* __restrict__ wts) {
  int idx = blockIdx.x * 256 + threadIdx.x;
  int n = idx >> 9;
  int c = (idx & 511) * 4;
  float4 v = *(const float4*)(ysf + (size_t)n * CDIM + c);
#pragma unroll
  for (int k = 0; k < 2; k++) {
    int slot = slot_of[n * 2 + k];
    float w = wts[n * 2 + k];
    ushort4 h = *(const ushort4*)(eo + (size_t)slot * CDIM + c);
    v.x += w * bf2f(h.x);
    v.y += w * bf2f(h.y);
    v.z += w * bf2f(h.z);
    v.w += w * bf2f(h.w);
  }
  *(float4*)(y + (size_t)n * CDIM + c) = v;
}

extern "C" void kernel_launch(void* const* d_in, const int* in_sizes, int n_in,
                              void* d_out, int out_size, void* d_ws, size_t ws_size,
                              hipStream_t stream) {
  const float* x   = (const float*)d_in[0];
  const float* gw  = (const float*)d_in[1];
  const float* w1  = (const float*)d_in[2];
  const float* w2  = (const float*)d_in[3];
  const float* w3  = (const float*)d_in[4];
  const float* sw1 = (const float*)d_in[5];
  const float* sw2 = (const float*)d_in[6];
  const float* sw3 = (const float*)d_in[7];
  float* y = (float*)d_out;

  char* ws = (char*)d_ws;
  size_t off = 0;
  auto alloc = [&](size_t b) -> void* {
    void* p = ws + off;
    off += (b + 255) & ~(size_t)255;
    return p;
  };
  unsigned short* xb    = (unsigned short*)alloc((size_t)N_TOK * CDIM * 2);
  unsigned short* wcat  = (unsigned short*)alloc((size_t)NEXP * ICAT * CDIM * 2);
  unsigned short* w3b   = (unsigned short*)alloc((size_t)NEXP * CDIM * IDIM * 2);
  unsigned short* swcat = (unsigned short*)alloc((size_t)SCAT * CDIM * 2);
  unsigned short* sw3b  = (unsigned short*)alloc((size_t)CDIM * ISDIM * 2);
  unsigned short* hs    = (unsigned short*)alloc((size_t)N_TOK * ISDIM * 2);
  unsigned short* he    = (unsigned short*)alloc((size_t)NEXP * CAP * IDIM * 2);
  float*          ysf   = (float*)alloc((size_t)N_TOK * CDIM * 4);
  int*   counts  = (int*)alloc(NEXP * 4);
  int*   list    = (int*)alloc((size_t)NEXP * CAP * 4);
  int*   slot_of = (int*)alloc((size_t)N_TOK * 2 * 4);
  float* wtsb    = (float*)alloc((size_t)N_TOK * 2 * 4);
  // alias: eo reuses wcat (dead after fc GEMM)
  unsigned short* eoB = wcat;

  hipMemsetAsync(counts, 0, NEXP * 4, stream);
  routing_kernel<<<N_TOK, 64, 0, stream>>>(x, gw, counts, list, slot_of, wtsb);

  // convert fc-side tensors only (x, w1/w2->wcat, sw1/sw2->swcat)
  cvt_all<<<32256, 256, 0, stream>>>(x, w1, w2, sw1, sw2, xb, wcat, swcat);

  // fc GEMM with fused silu-gate epilogue; z=12 converts w3/sw3 concurrently
  moe_gemm<1><<<dim3(88, 1, 13), 512, 0, stream>>>(
      xb, swcat, wcat, hs, he, hs, sw3b, he, w3b, ysf, eoB, list, counts,
      w3, sw3, w3b, sw3b);

  // proj GEMM: z 0..1 shared (long K first), z 2..9 experts
  moe_gemm<2><<<dim3(64, 1, 10), 512, 0, stream>>>(
      xb, swcat, wcat, hs, he, hs, sw3b, he, w3b, ysf, eoB, list, counts,
      nullptr, nullptr, nullptr, nullptr);

  // combine
  combine_kernel<<<(N_TOK * (CDIM / 4)) / 256, 256, 0, stream>>>(y, ysf, eoB, slot_of, wtsb);
}

// Round 19
// 567.383 us; speedup vs baseline: 1.0858x; 1.0046x over previous
//
#include <hip/hip_runtime.h>
#include <stdint.h>

#define N_TOK 4096
#define CDIM  2048
#define NEXP  8
#define IDIM  1408
#define ISDIM 2816
#define CAP   2048
#define ICAT  2816   // interleaved [w1;w2] rows per expert (128-row groups)
#define SCAT  5632   // interleaved [sw1;sw2] rows (2 col-half sections)

typedef __attribute__((ext_vector_type(8))) short bf16x8;
typedef __attribute__((ext_vector_type(4))) float f32x4;

#define GLOAD16(gp, lp) __builtin_amdgcn_global_load_lds( \
    (const __attribute__((address_space(1))) void*)(gp),  \
    (__attribute__((address_space(3))) void*)(lp), 16, 0, 0)

__device__ __forceinline__ unsigned short f2bf(float f) {
  union { float f; unsigned u; } c; c.f = f;
  return (unsigned short)((c.u + 0x7FFFu + ((c.u >> 16) & 1u)) >> 16);
}
__device__ __forceinline__ float bf2f(unsigned short h) {
  union { unsigned u; float f; } c; c.u = (unsigned)h << 16;
  return c.f;
}

__device__ __forceinline__ int xcd_swizzle(int orig, int nwg) {
  int q = nwg >> 3, r = nwg & 7;
  int xcd = orig & 7, idx = orig >> 3;
  return (xcd < r ? xcd * (q + 1) : r * (q + 1) + (xcd - r) * q) + idx;
}

// ---------------- fused fp32 -> bf16 convert + routing tail ----------------
// blocks [0,32256): convert x, w1/w2->wcat, sw1/sw2->swcat.
// blocks [32256,33280): routing — 4 tokens/block, one per 64-lane wave.
// (w3/sw3 conversion lives in the fc GEMM launch as z=12 — overlapped.)
__global__ __launch_bounds__(256) void cvt_all(
    const float* __restrict__ x, const float* __restrict__ w1,
    const float* __restrict__ w2,
    const float* __restrict__ sw1, const float* __restrict__ sw2,
    unsigned short* __restrict__ xb, unsigned short* __restrict__ wcat,
    unsigned short* __restrict__ swcat,
    const float* __restrict__ gw,
    int* __restrict__ counts, int* __restrict__ list,
    int* __restrict__ slot_of, float* __restrict__ wts) {
  const int b = blockIdx.x;
  const int t = threadIdx.x;
  if (b >= 32256) {
    // ---- routing: token n, all lanes of one wave ----
    const int n = (b - 32256) * 4 + (t >> 6);
    const int lane = t & 63;
    const float* xr = x + (size_t)n * CDIM;
    float s[NEXP];
#pragma unroll
    for (int e = 0; e < NEXP; e++) s[e] = 0.f;
    for (int c = lane; c < CDIM; c += 64) {
      float xv = xr[c];
#pragma unroll
      for (int e = 0; e < NEXP; e++) s[e] += xv * gw[e * CDIM + c];
    }
#pragma unroll
    for (int e = 0; e < NEXP; e++) {
      float v = s[e];
      for (int o = 32; o > 0; o >>= 1) v += __shfl_down(v, o);
      s[e] = v;
    }
    if (lane == 0) {
      float mx = s[0];
#pragma unroll
      for (int e = 1; e < NEXP; e++) mx = fmaxf(mx, s[e]);
      float p[NEXP], sum = 0.f;
#pragma unroll
      for (int e = 0; e < NEXP; e++) { p[e] = __expf(s[e] - mx); sum += p[e]; }
      int i0 = 0;
#pragma unroll
      for (int e = 1; e < NEXP; e++) if (p[e] > p[i0]) i0 = e;
      int i1 = (i0 == 0) ? 1 : 0;
#pragma unroll
      for (int e = 0; e < NEXP; e++) if (e != i0 && p[e] > p[i1]) i1 = e;
      float inv = 1.f / sum;
      int s0 = atomicAdd(&counts[i0], 1);
      int s1 = atomicAdd(&counts[i1], 1);
      if (s0 < CAP) list[i0 * CAP + s0] = n; else s0 = 0;
      if (s1 < CAP) list[i1 * CAP + s1] = n; else s1 = 0;
      slot_of[n * 2]     = i0 * CAP + s0;
      slot_of[n * 2 + 1] = i1 * CAP + s1;
      wts[n * 2]     = p[i0] * inv;
      wts[n * 2 + 1] = p[i1] * inv;
    }
    return;
  }
  const float* src;
  unsigned short* dst;
  if (b < 4096) {
    src = x + (size_t)b * 2048;  dst = xb + (size_t)b * 2048;
  } else if (b < 26624) {
    int g = b - 4096;
    int e = g / 2816, r = g - e * 2816;
    int dr;
    if (r < 1408) { src = w1 + ((size_t)e * 1408 + r) * 2048; dr = (r >> 7) * 256 + (r & 127); }
    else { int r2 = r - 1408; src = w2 + ((size_t)e * 1408 + r2) * 2048; dr = (r2 >> 7) * 256 + 128 + (r2 & 127); }
    dst = wcat + ((size_t)e * ICAT + dr) * 2048;
  } else {
    int g = b - 26624;
    int dr;
    if (g < 2816) {
      int zn = g >= 1408, rr = g - zn * 1408;
      src = sw1 + (size_t)g * 2048;
      dr = zn * 2816 + (rr >> 7) * 256 + (rr & 127);
    } else {
      int r = g - 2816;
      int zn = r >= 1408, rr = r - zn * 1408;
      src = sw2 + (size_t)r * 2048;
      dr = zn * 2816 + (rr >> 7) * 256 + 128 + (rr & 127);
    }
    dst = swcat + (size_t)dr * 2048;
  }
  size_t i = (size_t)t * 8;
  float4 v0 = *(const float4*)(src + i);
  float4 v1 = *(const float4*)(src + i + 4);
  bf16x8 o;
  o[0] = (short)f2bf(v0.x); o[1] = (short)f2bf(v0.y);
  o[2] = (short)f2bf(v0.z); o[3] = (short)f2bf(v0.w);
  o[4] = (short)f2bf(v1.x); o[5] = (short)f2bf(v1.y);
  o[6] = (short)f2bf(v1.z); o[7] = (short)f2bf(v1.w);
  *(bf16x8*)(dst + i) = o;
}

// ---------------- unified 8-phase deep-pipelined GEMM: Out = A @ B^T ----------------
// 256x256 tile, BK=64 (2 K-halves of 64B/row), 512 threads (8 waves, 2M x 4N).
// Best-measured core (R8/R15, ~591us standalone): 2 gloads per phase,
// ledger-exact vmcnt(8)/(4)/(0); T2 both-sides swizzle; setprio around MFMA;
// m225 accumulator recipe; fc epilogue h2-exchange XOR-swizzled (conflict-free).
// R18 (+20us): fc launch carries z=12 = grid-stride w3/sw3 fp32->bf16 convert,
// co-scheduled with the compute-bound GEMM blocks (fc at 16% HBM).
template <int PHASE>
__global__ __launch_bounds__(512) void moe_gemm(
    const unsigned short* __restrict__ xb,
    const unsigned short* __restrict__ swcat,
    const unsigned short* __restrict__ wcat,
    unsigned short* __restrict__ hs_out,
    unsigned short* __restrict__ he_out,
    const unsigned short* __restrict__ hs,
    const unsigned short* __restrict__ sw3b,
    const unsigned short* __restrict__ he,
    const unsigned short* __restrict__ w3b,
    float* __restrict__ ysf,
    unsigned short* __restrict__ eo,
    const int* __restrict__ list,
    const int* __restrict__ counts,
    const float* __restrict__ w3f,
    const float* __restrict__ sw3f,
    unsigned short* __restrict__ w3b_mut,
    unsigned short* __restrict__ sw3b_mut) {
  const int z = blockIdx.z;
  if (PHASE == 1 && z == 12) {
    // overlapped convert: w3 -> w3b, sw3 -> sw3b (grid-stride, 88 blocks)
    const size_t W3E  = (size_t)NEXP * CDIM * IDIM;          // 23,068,672
    const size_t TOTE = W3E + (size_t)CDIM * ISDIM;          // 28,835,840
    const size_t stride = (size_t)88 * 512 * 8;
    for (size_t i = ((size_t)blockIdx.x * 512 + threadIdx.x) * 8; i < TOTE; i += stride) {
      const float* s;
      unsigned short* d;
      if (i < W3E) { s = w3f + i; d = w3b_mut + i; }
      else         { s = sw3f + (i - W3E); d = sw3b_mut + (i - W3E); }
      float4 v0 = *(const float4*)s;
      float4 v1 = *(const float4*)(s + 4);
      bf16x8 o;
      o[0] = (short)f2bf(v0.x); o[1] = (short)f2bf(v0.y);
      o[2] = (short)f2bf(v0.z); o[3] = (short)f2bf(v0.w);
      o[4] = (short)f2bf(v1.x); o[5] = (short)f2bf(v1.y);
      o[6] = (short)f2bf(v1.z); o[7] = (short)f2bf(v1.w);
      *(bf16x8*)d = o;
    }
    return;
  }
  const unsigned short *A, *B;
  unsigned short* O = nullptr;
  float* Of = nullptr;
  int Ka, ldo;
  int cnt = 1 << 30;
  const int* lst = nullptr;
  int Mt, Nt;
  bool gath = false;
  if (PHASE == 1) {
    Mt = 8; Nt = 11; Ka = CDIM;
    if (z < 4) {
      int zm = z >> 1, zn = z & 1;
      A = xb + (size_t)zm * 2048 * CDIM;
      B = swcat + (size_t)zn * 2816 * CDIM;
      O = hs_out + (size_t)zm * 2048 * ISDIM + (size_t)zn * 1408;
      ldo = ISDIM;
    } else {
      int e = z - 4;
      cnt = counts[e]; if (cnt > CAP) cnt = CAP;
      lst = list + e * CAP;
      gath = true;
      A = xb;
      B = wcat + (size_t)e * ICAT * CDIM;
      O = he_out + (size_t)e * CAP * IDIM;
      ldo = IDIM;
    }
  } else {
    Mt = 8; Nt = 8;
    if (z < 2) {
      Ka = ISDIM;
      A = hs + (size_t)z * 2048 * ISDIM;
      B = sw3b;
      Of = ysf + (size_t)z * 2048 * CDIM;
      ldo = CDIM;
    } else {
      int e = z - 2;
      cnt = counts[e]; if (cnt > CAP) cnt = CAP;
      Ka = IDIM;
      A = he + (size_t)e * CAP * IDIM;
      B = w3b + (size_t)e * CDIM * IDIM;
      O = eo + (size_t)e * CAP * CDIM;
      ldo = CDIM;
    }
  }
  const int wg = xcd_swizzle(blockIdx.x, Mt * Nt);
  const int mt = wg % Mt, nt = wg / Mt;
  if (mt * 256 >= cnt) return;

  __shared__ __align__(16) char lds[2][2][2][16384]; // [buf][A|B][kk][256x64B]

  const int tid = threadIdx.x;
  const int srow = tid >> 2;
  const int c16  = (tid & 3) << 4;
  const int scol = c16 ^ (((srow >> 1) & 3) << 4);
  const char* aS[2];
  const char* bS[2];
#pragma unroll
  for (int j = 0; j < 2; j++) {
    int ar = mt * 256 + j * 128 + srow;
    if (PHASE == 1 && gath) ar = (ar < cnt) ? lst[ar] : lst[0];
    aS[j] = (const char*)A + (size_t)ar * Ka * 2 + scol;
    int br = nt * 256 + j * 128 + srow;
    bS[j] = (const char*)B + (size_t)br * Ka * 2 + scol;
  }
  auto stageA = [&](int buf, int kt, int h) {
    size_t kb = (size_t)kt * 128 + (size_t)(h << 6);
    char* aD = &lds[buf][0][h][0] + tid * 16;
    GLOAD16(aS[0] + kb, aD);
    GLOAD16(aS[1] + kb, aD + 8192);
  };
  auto stageB = [&](int buf, int kt, int h) {
    size_t kb = (size_t)kt * 128 + (size_t)(h << 6);
    char* bD = &lds[buf][1][h][0] + tid * 16;
    GLOAD16(bS[0] + kb, bD);
    GLOAD16(bS[1] + kb, bD + 8192);
  };

  const int lane = tid & 63, wid = tid >> 6;
  const int wr = wid >> 2, wc = wid & 3;   // 2 x 4 wave grid, per-wave 128x64
  const int lrow = lane & 15;
  const int klane = (lane >> 4) << 4;
  const int rsw = ((lrow >> 1) & 3) << 4;
  const int aOff = (wr * 128 + lrow) * 64 + (klane ^ rsw);
  const int bOff = (wc * 64 + lrow) * 64 + (klane ^ rsw);

  f32x4 acc[8][4];
#pragma unroll
  for (int mf = 0; mf < 8; mf++)
#pragma unroll
    for (int nf = 0; nf < 4; nf++) acc[mf][nf] = (f32x4){0.f, 0.f, 0.f, 0.f};

  // prologue: (0,kk0),(0,kk1),(1,kk0) staged; drain (0,kk0) [8 newer]
  stageA(0, 0, 0); stageB(0, 0, 0);
  stageA(0, 0, 1); stageB(0, 0, 1);
  stageA(1, 1, 0); stageB(1, 1, 0);
  asm volatile("s_waitcnt vmcnt(8)" ::: "memory");
  __builtin_amdgcn_s_barrier();

#define MFMA_Q(MB)                                                             \
  _Pragma("unroll")                                                            \
  for (int nf = 0; nf < 4; nf++)                                               \
    _Pragma("unroll")                                                          \
    for (int m = 0; m < 4; m++)                                                \
      acc[(MB) * 4 + m][nf] = __builtin_amdgcn_mfma_f32_16x16x32_bf16(         \
          aR[m], bR[nf], acc[(MB) * 4 + m][nf], 0, 0, 0);

  const int ntk = Ka >> 6;
  for (int t = 0; t < ntk; t++) {
    const int p = t & 1;
    const char* aK0 = &lds[p][0][0][0];
    const char* aK1 = &lds[p][0][1][0];
    const char* bK0 = &lds[p][1][0][0];
    const char* bK1 = &lds[p][1][1][0];
    bf16x8 aR[4], bR[4];
    // ---- P1: kk0, m-half 0 -> acc[0..3]; stage A(t+1,kk1) -> buf p^1
#pragma unroll
    for (int i = 0; i < 4; i++) aR[i] = *(const bf16x8*)(aK0 + aOff + i * 1024);
#pragma unroll
    for (int i = 0; i < 4; i++) bR[i] = *(const bf16x8*)(bK0 + bOff + i * 1024);
    if (t + 1 < ntk) stageA(p ^ 1, t + 1, 1);
    __builtin_amdgcn_s_barrier();
    asm volatile("s_waitcnt lgkmcnt(0)" ::: "memory");
    __builtin_amdgcn_s_setprio(1);
    MFMA_Q(0)
    __builtin_amdgcn_s_setprio(0);
    __builtin_amdgcn_s_barrier();
    // ---- P2: kk0, m-half 1 -> acc[4..7]; stage B(t+1,kk1); drain (t,kk1)
#pragma unroll
    for (int i = 0; i < 4; i++) aR[i] = *(const bf16x8*)(aK0 + aOff + (i + 4) * 1024);
    if (t + 1 < ntk) {
      stageB(p ^ 1, t + 1, 1);
      asm volatile("s_waitcnt vmcnt(8)" ::: "memory");
    } else {
      asm volatile("s_waitcnt vmcnt(0)" ::: "memory");
    }
    __builtin_amdgcn_s_barrier();
    asm volatile("s_waitcnt lgkmcnt(0)" ::: "memory");
    __builtin_amdgcn_s_setprio(1);
    MFMA_Q(1)
    __builtin_amdgcn_s_setprio(0);
    __builtin_amdgcn_s_barrier();
    // ---- P3: kk1, m-half 0 -> acc[0..3]; stage A(t+2,kk0) -> buf p
#pragma unroll
    for (int i = 0; i < 4; i++) aR[i] = *(const bf16x8*)(aK1 + aOff + i * 1024);
#pragma unroll
    for (int i = 0; i < 4; i++) bR[i] = *(const bf16x8*)(bK1 + bOff + i * 1024);
    if (t + 2 < ntk) stageA(p, t + 2, 0);
    __builtin_amdgcn_s_barrier();
    asm volatile("s_waitcnt lgkmcnt(0)" ::: "memory");
    __builtin_amdgcn_s_setprio(1);
    MFMA_Q(0)
    __builtin_amdgcn_s_setprio(0);
    __builtin_amdgcn_s_barrier();
    // ---- P4: kk1, m-half 1 -> acc[4..7]; stage B(t+2,kk0); drain (t+1,kk0)
#pragma unroll
    for (int i = 0; i < 4; i++) aR[i] = *(const bf16x8*)(aK1 + aOff + (i + 4) * 1024);
    if (t + 2 < ntk) {
      stageB(p, t + 2, 0);
      asm volatile("s_waitcnt vmcnt(8)" ::: "memory");
    } else if (t + 1 < ntk) {
      asm volatile("s_waitcnt vmcnt(4)" ::: "memory");
    }
    __builtin_amdgcn_s_barrier();
    asm volatile("s_waitcnt lgkmcnt(0)" ::: "memory");
    __builtin_amdgcn_s_setprio(1);
    MFMA_Q(1)
    __builtin_amdgcn_s_setprio(0);
    __builtin_amdgcn_s_barrier();
  }
#undef MFMA_Q

  const int r4 = (lane >> 4) * 4;
  if (PHASE == 1) {
    // fused gate: waves wc>=2 publish h2 (f32) via XOR-swizzled LDS, wc<2 combine.
    float* ldsF = (float*)&lds[0][0][0][0];      // 256 x 128 f32 = 128 KiB
    const int rbase = wr * 128 + r4;
    if (wc >= 2) {
      const int cb = (wc - 2) * 64;
#pragma unroll
      for (int mf = 0; mf < 8; mf++)
#pragma unroll
        for (int nf = 0; nf < 4; nf++) {
          int cc = cb + nf * 16 + lrow;
#pragma unroll
          for (int r = 0; r < 4; r++) {
            int rr = rbase + mf * 16 + r;
            ldsF[rr * 128 + (cc ^ (((rr >> 2) & 1) << 4))] = acc[mf][nf][r];
          }
        }
    }
    __syncthreads();
    if (wc < 2) {
      const int cb = wc * 64;
#pragma unroll
      for (int mf = 0; mf < 8; mf++) {
        int row0 = mt * 256 + wr * 128 + mf * 16 + r4;
#pragma unroll
        for (int nf = 0; nf < 4; nf++) {
          int cc = cb + nf * 16 + lrow;
          int col = nt * 128 + cc;
#pragma unroll
          for (int r = 0; r < 4; r++) {
            int rr = rbase + mf * 16 + r;
            float z1 = acc[mf][nf][r];
            float z2 = ldsF[rr * 128 + (cc ^ (((rr >> 2) & 1) << 4))];
            float gv = z1 / (1.f + __expf(-z1)) * z2;
            O[(size_t)(row0 + r) * ldo + col] = f2bf(gv);
          }
        }
      }
    }
  } else {
    const int rowb = mt * 256 + wr * 128;
    const int colb = nt * 256 + wc * 64;
#pragma unroll
    for (int mf = 0; mf < 8; mf++) {
      int row0 = rowb + mf * 16 + r4;
#pragma unroll
      for (int nf = 0; nf < 4; nf++) {
        int col = colb + nf * 16 + lrow;
#pragma unroll
        for (int r = 0; r < 4; r++) {
          if (z < 2)
            Of[(size_t)(row0 + r) * ldo + col] = acc[mf][nf][r];
          else
            O[(size_t)(row0 + r) * ldo + col] = f2bf(acc[mf][nf][r]);
        }
      }
    }
  }
}

// ---------------- combine: y = ys + sum_k w_k * eo[slot_k] ----------------
__global__ __launch_bounds__(256) void combine_kernel(
    float* __restrict__ y, const float* __restrict__ ysf,
    const unsigned short* __restrict__ eo,
    const int* __restrict__ slot_of, const float* __restrict__ wts) {
  int idx = blockIdx.x * 256 + threadIdx.x;
  int n = idx >> 9;
  int c = (idx & 511) * 4;
  float4 v = *(const float4*)(ysf + (size_t)n * CDIM + c);
#pragma unroll
  for (int k = 0; k < 2; k++) {
    int slot = slot_of[n * 2 + k];
    float w = wts[n * 2 + k];
    ushort4 h = *(const ushort4*)(eo + (size_t)slot * CDIM + c);
    v.x += w * bf2f(h.x);
    v.y += w * bf2f(h.y);
    v.z += w * bf2f(h.z);
    v.w += w * bf2f(h.w);
  }
  *(float4*)(y + (size_t)n * CDIM + c) = v;
}

extern "C" void kernel_launch(void* const* d_in, const int* in_sizes, int n_in,
                              void* d_out, int out_size, void* d_ws, size_t ws_size,
                              hipStream_t stream) {
  const float* x   = (const float*)d_in[0];
  const float* gw  = (const float*)d_in[1];
  const float* w1  = (const float*)d_in[2];
  const float* w2  = (const float*)d_in[3];
  const float* w3  = (const float*)d_in[4];
  const float* sw1 = (const float*)d_in[5];
  const float* sw2 = (const float*)d_in[6];
  const float* sw3 = (const float*)d_in[7];
  float* y = (float*)d_out;

  char* ws = (char*)d_ws;
  size_t off = 0;
  auto alloc = [&](size_t b) -> void* {
    void* p = ws + off;
    off += (b + 255) & ~(size_t)255;
    return p;
  };
  unsigned short* xb    = (unsigned short*)alloc((size_t)N_TOK * CDIM * 2);
  unsigned short* wcat  = (unsigned short*)alloc((size_t)NEXP * ICAT * CDIM * 2);
  unsigned short* w3b   = (unsigned short*)alloc((size_t)NEXP * CDIM * IDIM * 2);
  unsigned short* swcat = (unsigned short*)alloc((size_t)SCAT * CDIM * 2);
  unsigned short* sw3b  = (unsigned short*)alloc((size_t)CDIM * ISDIM * 2);
  unsigned short* hs    = (unsigned short*)alloc((size_t)N_TOK * ISDIM * 2);
  unsigned short* he    = (unsigned short*)alloc((size_t)NEXP * CAP * IDIM * 2);
  float*          ysf   = (float*)alloc((size_t)N_TOK * CDIM * 4);
  int*   counts  = (int*)alloc(NEXP * 4);
  int*   list    = (int*)alloc((size_t)NEXP * CAP * 4);
  int*   slot_of = (int*)alloc((size_t)N_TOK * 2 * 4);
  float* wtsb    = (float*)alloc((size_t)N_TOK * 2 * 4);
  // alias: eo reuses wcat (dead after fc GEMM)
  unsigned short* eoB = wcat;

  hipMemsetAsync(counts, 0, NEXP * 4, stream);

  // fused convert (x, w1/w2->wcat, sw1/sw2->swcat) + routing tail blocks
  cvt_all<<<33280, 256, 0, stream>>>(x, w1, w2, sw1, sw2, xb, wcat, swcat,
                                     gw, counts, list, slot_of, wtsb);

  // fc GEMM with fused silu-gate epilogue; z=12 converts w3/sw3 concurrently
  moe_gemm<1><<<dim3(88, 1, 13), 512, 0, stream>>>(
      xb, swcat, wcat, hs, he, hs, sw3b, he, w3b, ysf, eoB, list, counts,
      w3, sw3, w3b, sw3b);

  // proj GEMM: z 0..1 shared (long K first), z 2..9 experts
  moe_gemm<2><<<dim3(64, 1, 10), 512, 0, stream>>>(
      xb, swcat, wcat, hs, he, hs, sw3b, he, w3b, ysf, eoB, list, counts,
      nullptr, nullptr, nullptr, nullptr);

  // combine
  combine_kernel<<<(N_TOK * (CDIM / 4)) / 256, 256, 0, stream>>>(y, ysf, eoB, slot_of, wtsb);
}